// Round 4
// baseline (5256.907 us; speedup 1.0000x reference)
//
#include <hip/hip_runtime.h>
#include <hip/hip_bf16.h>

// GraphConvLayer: out = relu(A_norm @ (X@W + b))
// Reassociated: Y = A@X (sparse, ~22.5 nnz/row), out = relu(Y@W + rowsum(A)[n]*b[d])
// x: [1024,543,256] f32; W: [256,256] f32; b: [256]; A: [543,543] f32; out: [1024,543,256] f32
//
// R4: block = 192 output rows (3 blocks/bt). x streamed ONCE per block through LDS
// in 6 bf16 chunks of 96 rows. Y in registers (ylo[12]+yhi[12] f32x4/lane, static
// indexing only -> no scratch). MFMA in two 96-row halves reusing the x-chunk LDS.
// Epilogue bounces through LDS -> full-cache-line 512B/wave stores.

#define NND   543
#define NROWP 640
#define RPB   192           // rows per block
#define BPT   3             // blocks per bt
#define CH    96            // x chunk rows
#define NCH   6
#define CAPR  64            // CSR slots per row (mean ~22.5, +9 sigma)
#define BTOT  1024
#define GRID  (BTOT*BPT)    // 3072, %8==0 -> bijective XCD swizzle

typedef __attribute__((ext_vector_type(8))) short short8;
typedef __attribute__((ext_vector_type(4))) float f32x4;

// ---- workspace (bytes) ----
#define WS_ENT 0                          // uint2[640][64] = 327680  {m, f32bits(a)}
#define WS_ST  327680                     // u16[640][8]: st[0..6] chunk offsets, [7] overflow flag
#define WS_RS  337920                     // f32[640] rowsum
#define WS_W   340480                     // bf16 frags [16][8][64][8] = 131072
#define WS_NEED 471552

// ---- LDS (bytes) ----
#define L_BNC 49152                       // f32[16][132] = 8448 (epilogue bounce)
#define L_RS  57600                       // f32[192]
#define L_TOT 58368                       // [0,49152): x-chunk bf16[96][256] / Y-half swz

__device__ __forceinline__ unsigned short f2bf(float f) {   // RNE f32 -> bf16 bits
  unsigned int u = __builtin_bit_cast(unsigned int, f);
  u += 0x7fffu + ((u >> 16) & 1u);
  return (unsigned short)(u >> 16);
}
__device__ __forceinline__ float bflo(unsigned int u) { return __builtin_bit_cast(float, u << 16); }
__device__ __forceinline__ float bfhi(unsigned int u) { return __builtin_bit_cast(float, u & 0xffff0000u); }
__device__ __forceinline__ uint2 pack4(const f32x4 v) {
  uint2 u;
  u.x = (unsigned)f2bf(v.x) | ((unsigned)f2bf(v.y) << 16);
  u.y = (unsigned)f2bf(v.z) | ((unsigned)f2bf(v.w) << 16);
  return u;
}

// ---------------- prep: flat CSR + per-chunk offsets + rowsum (one wave/row) ----------------
__global__ void prep_csr(const float* __restrict__ A, char* __restrict__ ws) {
  const int wid = (blockIdx.x * blockDim.x + threadIdx.x) >> 6;
  const int lane = threadIdx.x & 63;
  if (wid >= NROWP) return;
  uint2* ep = (uint2*)(ws + WS_ENT) + (size_t)wid * CAPR;
  unsigned short* st = (unsigned short*)(ws + WS_ST) + wid * 8;
  float* rs = (float*)(ws + WS_RS);
  if (wid >= NND) {
    if (lane < 8) st[lane] = 0;
    if (lane == 0) rs[wid] = 0.f;
    return;
  }
  const float* arow = A + (size_t)wid * NND;
  float s = 0.f; int cnt = 0;
  unsigned short stc1 = 0, stc2 = 0, stc3 = 0, stc4 = 0, stc5 = 0;
  for (int m0 = 0; m0 < NND; m0 += 64) {
    const int m = m0 + lane;
    const float a = (m < NND) ? arow[m] : 0.f;
    s += a;
    const unsigned long long mask = __ballot(a != 0.f);
    // chunk boundaries 96,192,288,384,480 each crossed once
    if (m0 == 64)  stc1 = (unsigned short)(cnt + (int)__popcll(mask & ((1ull << 32) - 1ull)));
    if (m0 == 128) stc2 = (unsigned short)(cnt + (int)__popcll(mask));
    if (m0 == 256) stc3 = (unsigned short)(cnt + (int)__popcll(mask & ((1ull << 32) - 1ull)));
    if (m0 == 320) stc4 = (unsigned short)(cnt + (int)__popcll(mask));
    if (m0 == 448) stc5 = (unsigned short)(cnt + (int)__popcll(mask & ((1ull << 32) - 1ull)));
    if (a != 0.f) {
      const int idx = cnt + (int)__popcll(mask & ((1ull << lane) - 1ull));
      if (idx < CAPR) ep[idx] = make_uint2((unsigned)m, __builtin_bit_cast(unsigned, a));
    }
    cnt += (int)__popcll(mask);
  }
  #pragma unroll
  for (int o = 32; o > 0; o >>= 1) s += __shfl_xor(s, o);
  if (lane == 0) {
    st[0] = 0; st[1] = stc1; st[2] = stc2; st[3] = stc3; st[4] = stc4; st[5] = stc5;
    st[6] = (unsigned short)cnt;
    st[7] = (cnt > CAPR) ? (unsigned short)1 : (unsigned short)0;
    rs[wid] = s;
  }
}

// ---------------- prep: W -> bf16 MFMA B-fragments [g][ks][lane][8] ----------------
__global__ void prep_w(const float* __restrict__ W, char* __restrict__ ws) {
  const int t = blockIdx.x * 256 + threadIdx.x;
  if (t >= 16 * 8 * 64) return;
  const int lane = t & 63, ks = (t >> 6) & 7, g = t >> 9;
  const int krow = (lane >> 4) * 8, col = g * 16 + (lane & 15);
  unsigned short* dst = (unsigned short*)(ws + WS_W) + (size_t)t * 8;
  #pragma unroll
  for (int e = 0; e < 8; e++) dst[e] = f2bf(W[(ks * 32 + krow + e) * 256 + col]);
}

// ---------------- main ----------------
__global__ __launch_bounds__(512, 4)   // 8 waves; 2 blocks/CU (VGPR<=128, LDS 58KB)
void gcn_main(const float* __restrict__ x, const float* __restrict__ Wm,
              const float* __restrict__ bias, const float* __restrict__ A,
              float* __restrict__ out, const char* __restrict__ ws, int use_ws)
{
  __shared__ __align__(16) char lds[L_TOT];
  float* bnc = (float*)(lds + L_BNC);
  float* rsl = (float*)(lds + L_RS);

  const int tid = threadIdx.x;
  const int w = tid >> 6, lane = tid & 63;
  const int cl = lane & 15, krow = (lane >> 4) * 8;

  const int p = blockIdx.x;
  const int L = (p & 7) * (GRID / 8) + (p >> 3);
  const int bt = L / BPT;
  const int tile = L - bt * BPT;
  const int n0 = tile * RPB;

  const float* xbt = x + (size_t)bt * (NND * 256);
  const uint2* entp = (const uint2*)(ws + WS_ENT);
  const unsigned short* stp = (const unsigned short*)(ws + WS_ST);

  if (tid < RPB) rsl[tid] = use_ws ? ((const float*)(ws + WS_RS))[n0 + tid] : 0.f;

  // ---- gather: Y = A@X, x streamed once through LDS in 6 bf16 chunks ----
  f32x4 ylo[12], yhi[12];
  #pragma unroll
  for (int i = 0; i < 12; i++) { ylo[i] = (f32x4){0.f,0.f,0.f,0.f}; yhi[i] = (f32x4){0.f,0.f,0.f,0.f}; }

  for (int c = 0; c < NCH; ++c) {
    const int mbase = c * CH;
    const int rows = min(CH, NND - mbase);
    __syncthreads();   // previous chunk's gather reads done
    #pragma unroll
    for (int k2 = 0; k2 < 12; ++k2) {      // stage 96x256 f32 -> bf16 LDS, coalesced
      const int fl = tid + k2 * 512;
      const int row = fl >> 6, f4 = fl & 63;
      if (row < rows) {
        const float4 v = *(const float4*)(xbt + (size_t)(mbase + row) * 256 + f4 * 4);
        uint2 u;
        u.x = (unsigned)f2bf(v.x) | ((unsigned)f2bf(v.y) << 16);
        u.y = (unsigned)f2bf(v.z) | ((unsigned)f2bf(v.w) << 16);
        *(uint2*)(lds + (row << 9) + (f4 << 3)) = u;
      }
    }
    __syncthreads();

    auto gatherRow = [&](f32x4& y, const int n) {
      bool dense = (!use_ws) && (n < NND);
      if (use_ws) {
        const unsigned short* stn = stp + n * 8;
        if (stn[7]) {
          dense = (n < NND);                 // overflow row
        } else {
          const int j1 = stn[c + 1];
          int j = stn[c];
          const uint2* ep = entp + (size_t)n * CAPR;
          for (; j + 1 < j1; j += 2) {
            const uint2 e0 = ep[j], e1 = ep[j + 1];
            const uint2 u0 = *(const uint2*)(lds + (((int)e0.x - mbase) << 9) + (lane << 3));
            const uint2 u1 = *(const uint2*)(lds + (((int)e1.x - mbase) << 9) + (lane << 3));
            const float a0 = __builtin_bit_cast(float, e0.y);
            const float a1 = __builtin_bit_cast(float, e1.y);
            y.x += a0 * bflo(u0.x); y.y += a0 * bfhi(u0.x);
            y.z += a0 * bflo(u0.y); y.w += a0 * bfhi(u0.y);
            y.x += a1 * bflo(u1.x); y.y += a1 * bfhi(u1.x);
            y.z += a1 * bflo(u1.y); y.w += a1 * bfhi(u1.y);
          }
          if (j < j1) {
            const uint2 e0 = ep[j];
            const uint2 u0 = *(const uint2*)(lds + (((int)e0.x - mbase) << 9) + (lane << 3));
            const float a0 = __builtin_bit_cast(float, e0.y);
            y.x += a0 * bflo(u0.x); y.y += a0 * bfhi(u0.x);
            y.z += a0 * bflo(u0.y); y.w += a0 * bfhi(u0.y);
          }
          return;
        }
      }
      if (dense) {
        const float* arow = A + (size_t)n * NND + mbase;
        for (int m = 0; m < rows; ++m) {
          const float a = arow[m];
          if (a != 0.f) {
            const uint2 u = *(const uint2*)(lds + (m << 9) + (lane << 3));
            y.x += a * bflo(u.x); y.y += a * bfhi(u.x);
            y.z += a * bflo(u.y); y.w += a * bfhi(u.y);
          }
        }
      }
    };
    #pragma unroll
    for (int rr = 0; rr < 12; ++rr) gatherRow(ylo[rr], n0 + w * 12 + rr);
    #pragma unroll
    for (int rr = 0; rr < 12; ++rr) gatherRow(yhi[rr], n0 + 96 + w * 12 + rr);
  }

  if (!use_ws) {     // fallback rowsums (no extra register arrays)
    __syncthreads();
    for (int r = w; r < RPB; r += 8) {
      const int n = n0 + r;
      float s = 0.f;
      if (n < NND) for (int m = lane; m < NND; m += 64) s += A[(size_t)n * NND + m];
      #pragma unroll
      for (int o = 32; o > 0; o >>= 1) s += __shfl_xor(s, o);
      if (lane == 0) rsl[r] = s;
    }
  }

  // ---- two 96-row halves: Y -> LDS (bf16, XOR-swz) -> MFMA -> bounce -> store ----
  auto mfmaHalf = [&](const int h) {
    for (int dt = 0; dt < 2; ++dt) {
      const int d0 = dt * 128 + w * 16 + cl;
      short8 wf[8];
      if (use_ws) {
        const int g = dt * 8 + w;
        #pragma unroll
        for (int ks = 0; ks < 8; ++ks)
          wf[ks] = *(const short8*)(ws + WS_W + (size_t)(((g * 8 + ks) * 64 + lane) << 4));
      } else {
        #pragma unroll
        for (int ks = 0; ks < 8; ++ks) {
          #pragma unroll
          for (int e = 0; e < 8; ++e)
            wf[ks][e] = (short)f2bf(Wm[(ks * 32 + krow + e) * 256 + d0]);
        }
      }
      f32x4 acc[6];
      #pragma unroll
      for (int s6 = 0; s6 < 6; ++s6) acc[s6] = (f32x4){0.f,0.f,0.f,0.f};
      #pragma unroll
      for (int ks = 0; ks < 8; ++ks) {
        #pragma unroll
        for (int s6 = 0; s6 < 6; ++s6) {
          const int r = s6 * 16 + cl;
          const int kb = (ks * 64 + krow * 2) ^ ((r & 7) << 4);
          const short8 af = *(const short8*)(lds + r * 512 + kb);
          acc[s6] = __builtin_amdgcn_mfma_f32_16x16x32_bf16(af, wf[ks], acc[s6], 0, 0, 0);
        }
      }
      const float bv = bias[d0];
      #pragma unroll
      for (int s6 = 0; s6 < 6; ++s6) {
        __syncthreads();
        #pragma unroll
        for (int q = 0; q < 4; ++q) {
          const int row16 = (lane >> 4) * 4 + q;   // C/D: col=lane&15, row=(lane>>4)*4+q
          const float v = acc[s6][q] + rsl[h * 96 + s6 * 16 + row16] * bv;
          bnc[row16 * 132 + w * 16 + cl] = fmaxf(v, 0.f);
        }
        __syncthreads();
        const int rowg = 2 * w + (lane >> 5);
        const int colf = (lane & 31) * 4;
        const int n = n0 + h * 96 + s6 * 16 + rowg;
        if (n < NND)
          *(f32x4*)(out + ((size_t)bt * NND + n) * 256 + dt * 128 + colf) =
              *(const f32x4*)(bnc + rowg * 132 + colf);
      }
    }
  };

  __syncthreads();
  #pragma unroll
  for (int rr = 0; rr < 12; ++rr) {        // ylo -> Y-LDS (overlays x-chunk buffer)
    const int r = w * 12 + rr;
    *(uint2*)(lds + r * 512 + ((lane * 8) ^ ((r & 7) << 4))) = pack4(ylo[rr]);
  }
  __syncthreads();
  mfmaHalf(0);
  __syncthreads();
  #pragma unroll
  for (int rr = 0; rr < 12; ++rr) {        // yhi -> Y-LDS
    const int r = w * 12 + rr;
    *(uint2*)(lds + r * 512 + ((lane * 8) ^ ((r & 7) << 4))) = pack4(yhi[rr]);
  }
  __syncthreads();
  mfmaHalf(1);
}

extern "C" void kernel_launch(void* const* d_in, const int* in_sizes, int n_in,
                              void* d_out, int out_size, void* d_ws, size_t ws_size,
                              hipStream_t stream) {
  const float* x  = (const float*)d_in[0];
  const float* Wm = (const float*)d_in[1];
  const float* b  = (const float*)d_in[2];
  const float* A  = (const float*)d_in[3];
  float* out = (float*)d_out;
  const int use_ws = (d_ws != nullptr && ws_size >= (size_t)WS_NEED) ? 1 : 0;
  if (use_ws) {
    prep_csr<<<(NROWP * 64 + 255) / 256, 256, 0, stream>>>(A, (char*)d_ws);
    prep_w<<<(16 * 8 * 64 + 255) / 256, 256, 0, stream>>>(Wm, (char*)d_ws);
  }
  gcn_main<<<GRID, 512, 0, stream>>>(x, Wm, b, A, out, (const char*)d_ws, use_ws);
}